// Round 3
// baseline (523.088 us; speedup 1.0000x reference)
//
#include <hip/hip_runtime.h>
#include <hip/hip_bf16.h>
#include <stdint.h>

#define B_ 4
#define S_ 1024
#define D_ 1024
#define H_ 4096
#define E_ 8
#define T_ (B_*S_)   // 4096 tokens

#define BM 128
#define BN 128
#define BK 64        // 128 bytes of bf16 per row per tile

typedef __bf16 bf16x8 __attribute__((ext_vector_type(8)));
typedef float f32x4 __attribute__((ext_vector_type(4)));
typedef unsigned short ushort8 __attribute__((ext_vector_type(8)));

__device__ __forceinline__ unsigned short f2bf(float f) {
  union { float f; uint32_t u; } v; v.f = f;
  uint32_t u = v.u;
  u += 0x7fff + ((u >> 16) & 1);   // round-to-nearest-even
  return (unsigned short)(u >> 16);
}

// async global->LDS, 16B per lane; LDS dest is WAVE-UNIFORM base, HW scatters lane*16
__device__ __forceinline__ void gl16(const void* g, void* l) {
  __builtin_amdgcn_global_load_lds(
      (const __attribute__((address_space(1))) void*)g,
      (__attribute__((address_space(3))) void*)l,
      16, 0, 0);
}

// ---------------- x fp32 -> bf16 ----------------
__global__ __launch_bounds__(256) void conv_x_kernel(
    const float* __restrict__ x, unsigned short* __restrict__ xb) {
  size_t i = ((size_t)blockIdx.x * 256 + threadIdx.x) * 8;
  const float4* s = (const float4*)(x + i);
  float4 v0 = s[0], v1 = s[1];
  ushort8 w;
  w[0]=f2bf(v0.x); w[1]=f2bf(v0.y); w[2]=f2bf(v0.z); w[3]=f2bf(v0.w);
  w[4]=f2bf(v1.x); w[5]=f2bf(v1.y); w[6]=f2bf(v1.z); w[7]=f2bf(v1.w);
  *(ushort8*)(xb + i) = w;
}

// ---------------- W fp32 [E][R][C] -> bf16 [E][C][R] ----------------
__global__ __launch_bounds__(256) void transpose_conv(
    const float* __restrict__ in, unsigned short* __restrict__ outp,
    int R, int C) {
  __shared__ float tile[64][68];
  const int e = blockIdx.z;
  const size_t eoff = (size_t)e * R * C;
  const int r0 = blockIdx.y * 64, c0 = blockIdx.x * 64;
  const int t = threadIdx.x;
  {
    const int r = t >> 2, cq = (t & 3) * 16;
    const float4* s4 = (const float4*)(in + eoff + (size_t)(r0 + r) * C + (c0 + cq));
#pragma unroll
    for (int i = 0; i < 4; ++i)
      *(float4*)&tile[r][cq + i * 4] = s4[i];
  }
  __syncthreads();
  {
    const int c = t >> 2, r8 = (t & 3) * 16;
    unsigned short* dst = outp + eoff + (size_t)(c0 + c) * R + (r0 + r8);
    ushort8 w0, w1;
#pragma unroll
    for (int j = 0; j < 8; ++j) {
      w0[j] = f2bf(tile[r8 + j][c]);
      w1[j] = f2bf(tile[r8 + 8 + j][c]);
    }
    *(ushort8*)dst = w0;
    *(ushort8*)(dst + 8) = w1;
  }
}

// ---------------- gating: scores + top-2 routing ----------------
__global__ __launch_bounds__(256) void gating_kernel(
    const float* __restrict__ x, const float* __restrict__ Wg,
    const float* __restrict__ bg, float* __restrict__ scores,
    int* __restrict__ cnt, int* __restrict__ lists) {
  int t = blockIdx.x * 4 + (threadIdx.x >> 6);
  int l = threadIdx.x & 63;
  float acc[E_];
#pragma unroll
  for (int e = 0; e < E_; ++e) acc[e] = 0.f;
  const float* xr = x + (size_t)t * D_;
  for (int k = l; k < D_; k += 64) {
    float xv = xr[k];
    const float4* w = (const float4*)(Wg + (size_t)k * E_);
    float4 w0 = w[0], w1 = w[1];
    acc[0] += xv * w0.x; acc[1] += xv * w0.y; acc[2] += xv * w0.z; acc[3] += xv * w0.w;
    acc[4] += xv * w1.x; acc[5] += xv * w1.y; acc[6] += xv * w1.z; acc[7] += xv * w1.w;
  }
#pragma unroll
  for (int off = 32; off > 0; off >>= 1)
#pragma unroll
    for (int e = 0; e < E_; ++e) acc[e] += __shfl_xor(acc[e], off, 64);
  if (l == 0) {
    float s[E_];
#pragma unroll
    for (int e = 0; e < E_; ++e) {
      s[e] = acc[e] + bg[e];
      scores[(size_t)t * E_ + e] = s[e];
    }
    int i1 = 0; float m1 = -1e30f;
#pragma unroll
    for (int e = 0; e < E_; ++e) if (s[e] > m1) { m1 = s[e]; i1 = e; }
    int i2 = -1; float m2 = -1e30f;
#pragma unroll
    for (int e = 0; e < E_; ++e) if (e != i1 && s[e] > m2) { m2 = s[e]; i2 = e; }
    int p1 = atomicAdd(&cnt[i1], 1); lists[i1 * T_ + p1] = t;
    int p2 = atomicAdd(&cnt[i2], 1); lists[i2 * T_ + p2] = t;
  }
}

__global__ void scan_kernel(const int* __restrict__ cnt, int* __restrict__ off) {
  if (threadIdx.x == 0) {
    int o = 0;
    for (int e = 0; e < E_; ++e) { off[e] = o; o += cnt[e]; }
  }
}

// ---------------- grouped per-expert GEMM (2-phase double-buffered) ----------------
// LDS image per buffer: [row][64k] bf16, 128B/row, swizzle ((row&7)<<4) baked into
// the per-lane GLOBAL source address (gload_lds writes linearly), same XOR on reads.
template <int LAYER>
__global__ __launch_bounds__(256) void ffn_gemm(
    const unsigned short* __restrict__ xb,
    const unsigned short* __restrict__ hbuf,
    const unsigned short* __restrict__ WT,
    const float* __restrict__ bias,
    const int* __restrict__ cnt, const int* __restrict__ off,
    const int* __restrict__ lists,
    unsigned short* __restrict__ hout,
    float* __restrict__ out)
{
  constexpr int K = (LAYER == 1) ? D_ : H_;
  constexpr int N = (LAYER == 1) ? H_ : D_;
  const int e  = blockIdx.z;
  const int m0 = blockIdx.y * BM;
  const int n0 = blockIdx.x * BN;
  const int count = cnt[e];
  if (m0 >= count) return;
  const int oe = off[e];
  const int* lst = lists + e * T_;

  __shared__ unsigned short sA[2][BM * BK];   // 2 x 16 KB
  __shared__ unsigned short sB[2][BN * BK];   // 2 x 16 KB

  const int tid  = threadIdx.x;
  const int lane = tid & 63;
  const int wv   = tid >> 6;
  const int wm   = (wv >> 1) * 64, wn = (wv & 1) * 64;

  // staging addressing: per wave 4 issues each for A and B; issue i -> rows wv*32+i*8..+7
  const int srow = lane >> 3;
  const int schunk = (lane & 7) * 16;
  const int sgoff = schunk ^ (srow << 4);

  const char* arow[4];
  const char* brow[4];
#pragma unroll
  for (int i = 0; i < 4; ++i) {
    int r  = wv * 32 + i * 8 + srow;
    int gr = m0 + r;
    if (LAYER == 1) {
      int tok = (gr < count) ? lst[gr] : lst[m0];
      arow[i] = (const char*)(xb + (size_t)tok * K);
    } else {
      int rr = (gr < count) ? gr : m0;
      arow[i] = (const char*)(hbuf + (size_t)(oe + rr) * K);
    }
    brow[i] = (const char*)(WT + (size_t)e * N * K + (size_t)(n0 + r) * K);
  }

  // fragment addressing
  const int lrow = lane & 15;
  const int kg   = lane >> 4;
  const int fswz = (lrow & 7) << 4;

  f32x4 acc[4][4];
#pragma unroll
  for (int i = 0; i < 4; ++i)
#pragma unroll
    for (int j = 0; j < 4; ++j) acc[i][j] = (f32x4){0.f, 0.f, 0.f, 0.f};

  auto stage = [&](int buf, int kt) {
    const int kb = kt * 2;
#pragma unroll
    for (int i = 0; i < 4; ++i) {
      gl16(arow[i] + kb + sgoff, (char*)&sA[buf][0] + (wv * 32 + i * 8) * 128);
      gl16(brow[i] + kb + sgoff, (char*)&sB[buf][0] + (wv * 32 + i * 8) * 128);
    }
  };
  auto compute = [&](int buf) {
#pragma unroll
    for (int ks = 0; ks < 2; ++ks) {
      bf16x8 af[4], bfm[4];
      const int kbyte = ks * 64 + kg * 16;
#pragma unroll
      for (int i = 0; i < 4; ++i) {
        int ra = wm + i * 16 + lrow;
        int rb = wn + i * 16 + lrow;
        af[i]  = *(const bf16x8*)((const char*)&sA[buf][0] + ra * 128 + (kbyte ^ fswz));
        bfm[i] = *(const bf16x8*)((const char*)&sB[buf][0] + rb * 128 + (kbyte ^ fswz));
      }
#pragma unroll
      for (int i = 0; i < 4; ++i)
#pragma unroll
        for (int j = 0; j < 4; ++j)
          acc[i][j] = __builtin_amdgcn_mfma_f32_16x16x32_bf16(af[i], bfm[j], acc[i][j], 0, 0, 0);
    }
  };

  // 2-phase pipeline: prefetch next tile BEFORE computing current; the
  // end-of-iteration __syncthreads drains vmcnt AFTER compute has hidden it.
  stage(0, 0);
  __syncthreads();
  for (int kt = 0; kt < K; kt += 2 * BK) {
    if (kt + BK < K) stage(1, kt + BK);
    compute(0);
    __syncthreads();
    if (kt + BK < K) {
      if (kt + 2 * BK < K) stage(0, kt + 2 * BK);
      compute(1);
      __syncthreads();
    }
  }

  // ---- epilogue ----
  const int rbase = 4 * kg;
#pragma unroll
  for (int i = 0; i < 4; ++i) {
#pragma unroll
    for (int r = 0; r < 4; ++r) {
      int row  = wm + i * 16 + rbase + r;
      int grow = m0 + row;
      if (grow < count) {
#pragma unroll
        for (int j = 0; j < 4; ++j) {
          int col  = wn + j * 16 + lrow;
          int gcol = n0 + col;
          float v = acc[i][j][r] + bias[(size_t)e * N + gcol];
          if (LAYER == 1) {
            v = v > 0.f ? v : 0.f;
            hout[(size_t)(oe + grow) * H_ + gcol] = f2bf(v);
          } else {
            int tok = lst[grow];
            atomicAdd(&out[(size_t)tok * D_ + gcol], v);
          }
        }
      }
    }
  }
}

extern "C" void kernel_launch(void* const* d_in, const int* in_sizes, int n_in,
                              void* d_out, int out_size, void* d_ws, size_t ws_size,
                              hipStream_t stream) {
  (void)in_sizes; (void)n_in; (void)out_size; (void)ws_size;
  const float* x  = (const float*)d_in[0];
  const float* W1 = (const float*)d_in[1];
  const float* b1 = (const float*)d_in[2];
  const float* W2 = (const float*)d_in[3];
  const float* b2 = (const float*)d_in[4];
  const float* Wg = (const float*)d_in[5];
  const float* bg = (const float*)d_in[6];

  float* out    = (float*)d_out;               // [T,D]
  float* scores = out + (size_t)T_ * D_;       // [T,E]

  char* ws = (char*)d_ws;
  int* cnt   = (int*)ws;                                  // 32 B
  int* off   = (int*)(ws + 32);                           // 32 B
  int* lists = (int*)(ws + 64);                           // 128 KB
  unsigned short* xb   = (unsigned short*)(ws + 131200);              // 8 MB
  unsigned short* hbuf = (unsigned short*)(ws + 131200 + 8388608);    // 64 MB [8192][4096]
  unsigned short* WT   = (unsigned short*)(ws + 131200 + 8388608 + 67108864); // 64 MB shared W1T/W2T

  hipMemsetAsync(out, 0, (size_t)T_ * D_ * sizeof(float), stream);
  hipMemsetAsync(cnt, 0, 64, stream);

  conv_x_kernel<<<(T_ * D_) / (256 * 8), 256, 0, stream>>>(x, xb);
  gating_kernel<<<T_ / 4, 256, 0, stream>>>(x, Wg, bg, scores, cnt, lists);
  scan_kernel<<<1, 64, 0, stream>>>(cnt, off);

  // W1 [E,1024,4096] -> W1T [E,4096,1024]
  transpose_conv<<<dim3(H_ / 64, D_ / 64, E_), 256, 0, stream>>>(W1, WT, D_, H_);
  ffn_gemm<1><<<dim3(H_ / BN, T_ / BM, E_), 256, 0, stream>>>(
      xb, hbuf, WT, b1, cnt, off, lists, hbuf, nullptr);

  // W2 [E,4096,1024] -> W2T [E,1024,4096]  (reuses WT after gemm1)
  transpose_conv<<<dim3(D_ / 64, H_ / 64, E_), 256, 0, stream>>>(W2, WT, H_, D_);
  ffn_gemm<2><<<dim3(D_ / BN, T_ / BM, E_), 256, 0, stream>>>(
      xb, hbuf, WT, b2, cnt, off, lists, nullptr, out);
}

// Round 4
// 477.025 us; speedup vs baseline: 1.0966x; 1.0966x over previous
//
#include <hip/hip_runtime.h>
#include <hip/hip_bf16.h>
#include <stdint.h>

#define B_ 4
#define S_ 1024
#define D_ 1024
#define H_ 4096
#define E_ 8
#define T_ (B_*S_)   // 4096 tokens

#define BM 256
#define BN 256
#define BK 64        // 128 bytes of bf16 per row per K-tile

typedef __bf16 bf16x8 __attribute__((ext_vector_type(8)));
typedef float f32x4 __attribute__((ext_vector_type(4)));
typedef unsigned short ushort8 __attribute__((ext_vector_type(8)));

__device__ __forceinline__ unsigned short f2bf(float f) {
  union { float f; uint32_t u; } v; v.f = f;
  uint32_t u = v.u;
  u += 0x7fff + ((u >> 16) & 1);   // round-to-nearest-even
  return (unsigned short)(u >> 16);
}

// async global->LDS, 16B per lane; LDS dest is WAVE-UNIFORM base, HW scatters lane*16
__device__ __forceinline__ void gl16(const void* g, void* l) {
  __builtin_amdgcn_global_load_lds(
      (const __attribute__((address_space(1))) void*)g,
      (__attribute__((address_space(3))) void*)l,
      16, 0, 0);
}
#define MEMFENCE asm volatile("" ::: "memory")

// ---------------- x fp32 -> bf16 ----------------
__global__ __launch_bounds__(256) void conv_x_kernel(
    const float* __restrict__ x, unsigned short* __restrict__ xb) {
  size_t i = ((size_t)blockIdx.x * 256 + threadIdx.x) * 8;
  const float4* s = (const float4*)(x + i);
  float4 v0 = s[0], v1 = s[1];
  ushort8 w;
  w[0]=f2bf(v0.x); w[1]=f2bf(v0.y); w[2]=f2bf(v0.z); w[3]=f2bf(v0.w);
  w[4]=f2bf(v1.x); w[5]=f2bf(v1.y); w[6]=f2bf(v1.z); w[7]=f2bf(v1.w);
  *(ushort8*)(xb + i) = w;
}

// ---------------- W fp32 [E][R][C] -> bf16 [E][C][R] ----------------
__global__ __launch_bounds__(256) void transpose_conv(
    const float* __restrict__ in, unsigned short* __restrict__ outp,
    int R, int C) {
  __shared__ float tile[64][68];
  const int e = blockIdx.z;
  const size_t eoff = (size_t)e * R * C;
  const int r0 = blockIdx.y * 64, c0 = blockIdx.x * 64;
  const int t = threadIdx.x;
  {
    const int r = t >> 2, cq = (t & 3) * 16;
    const float4* s4 = (const float4*)(in + eoff + (size_t)(r0 + r) * C + (c0 + cq));
#pragma unroll
    for (int i = 0; i < 4; ++i)
      *(float4*)&tile[r][cq + i * 4] = s4[i];
  }
  __syncthreads();
  {
    const int c = t >> 2, r8 = (t & 3) * 16;
    unsigned short* dst = outp + eoff + (size_t)(c0 + c) * R + (r0 + r8);
    ushort8 w0, w1;
#pragma unroll
    for (int j = 0; j < 8; ++j) {
      w0[j] = f2bf(tile[r8 + j][c]);
      w1[j] = f2bf(tile[r8 + 8 + j][c]);
    }
    *(ushort8*)dst = w0;
    *(ushort8*)(dst + 8) = w1;
  }
}

// ---------------- gating: scores + top-2 routing ----------------
__global__ __launch_bounds__(256) void gating_kernel(
    const float* __restrict__ x, const float* __restrict__ Wg,
    const float* __restrict__ bg, float* __restrict__ scores,
    int* __restrict__ cnt, int* __restrict__ lists) {
  int t = blockIdx.x * 4 + (threadIdx.x >> 6);
  int l = threadIdx.x & 63;
  float acc[E_];
#pragma unroll
  for (int e = 0; e < E_; ++e) acc[e] = 0.f;
  const float* xr = x + (size_t)t * D_;
  for (int k = l; k < D_; k += 64) {
    float xv = xr[k];
    const float4* w = (const float4*)(Wg + (size_t)k * E_);
    float4 w0 = w[0], w1 = w[1];
    acc[0] += xv * w0.x; acc[1] += xv * w0.y; acc[2] += xv * w0.z; acc[3] += xv * w0.w;
    acc[4] += xv * w1.x; acc[5] += xv * w1.y; acc[6] += xv * w1.z; acc[7] += xv * w1.w;
  }
#pragma unroll
  for (int off = 32; off > 0; off >>= 1)
#pragma unroll
    for (int e = 0; e < E_; ++e) acc[e] += __shfl_xor(acc[e], off, 64);
  if (l == 0) {
    float s[E_];
#pragma unroll
    for (int e = 0; e < E_; ++e) {
      s[e] = acc[e] + bg[e];
      scores[(size_t)t * E_ + e] = s[e];
    }
    int i1 = 0; float m1 = -1e30f;
#pragma unroll
    for (int e = 0; e < E_; ++e) if (s[e] > m1) { m1 = s[e]; i1 = e; }
    int i2 = -1; float m2 = -1e30f;
#pragma unroll
    for (int e = 0; e < E_; ++e) if (e != i1 && s[e] > m2) { m2 = s[e]; i2 = e; }
    int p1 = atomicAdd(&cnt[i1], 1); lists[i1 * T_ + p1] = t;
    int p2 = atomicAdd(&cnt[i2], 1); lists[i2 * T_ + p2] = t;
  }
}

__global__ void scan_kernel(const int* __restrict__ cnt, int* __restrict__ off) {
  if (threadIdx.x == 0) {
    int o = 0;
    for (int e = 0; e < E_; ++e) { off[e] = o; o += cnt[e]; }
  }
}

// ---------------- grouped per-expert GEMM: 256^2 tile, counted-vmcnt pipeline ----
// 512 thr = 8 waves (2M x 4N), per-wave 128x64 output (8x4 frags of 16x16).
// LDS per buffer: A 256x64 bf16 (32KB) + B 256x64 (32KB); 2 buffers = 128KB.
// Rows are 128B; swizzle byte ^= ((row&7)<<4) baked into per-lane GLOBAL src
// (gload_lds writes linearly) and applied on ds_read.  Raw s_barrier + counted
// s_waitcnt vmcnt(8): tile t+2 staged into the buffer tile t just vacated;
// loads for t+1 stay in flight across the MFMA cluster (never drain to 0).
template <int LAYER, int SPLITK>
__global__ __launch_bounds__(512, 2) void ffn_gemm(
    const unsigned short* __restrict__ xb,
    const unsigned short* __restrict__ hbuf,
    const unsigned short* __restrict__ WT,
    const float* __restrict__ bias,
    const int* __restrict__ cnt, const int* __restrict__ off,
    const int* __restrict__ lists,
    unsigned short* __restrict__ hout,
    float* __restrict__ out)
{
  constexpr int K = (LAYER == 1) ? D_ : H_;
  constexpr int N = (LAYER == 1) ? H_ : D_;
  constexpr int KS = K / SPLITK;
  constexpr int NT = KS / BK;

  const int e    = blockIdx.z;
  const int nt_  = blockIdx.x % (N / BN);
  const int sp   = blockIdx.x / (N / BN);
  const int n0   = nt_ * BN;
  const int m0   = blockIdx.y * BM;
  const int k0   = sp * KS;
  const int count = cnt[e];
  if (m0 >= count) return;
  const int oe = off[e];
  const int* lst = lists + e * T_;

  __shared__ unsigned short sA[2][BM * BK];   // 2 x 32 KB
  __shared__ unsigned short sB[2][BN * BK];   // 2 x 32 KB

  const int tid  = threadIdx.x;
  const int lane = tid & 63;
  const int wv   = tid >> 6;
  const int wm   = (wv >> 2) * 128;
  const int wn   = (wv & 3) * 64;

  // staging: 4 issues per matrix per K-tile; issue i covers rows i*64 + wv*8 .. +7
  const int srow   = lane >> 3;
  const int schunk = (lane & 7) * 16;
  const int sgoff  = schunk ^ (srow << 4);

  const char* arow[4];
  const char* brow[4];
#pragma unroll
  for (int i = 0; i < 4; ++i) {
    int r  = i * 64 + wv * 8 + srow;
    int gr = m0 + r;
    if (LAYER == 1) {
      int tok = (gr < count) ? lst[gr] : lst[m0];
      arow[i] = (const char*)(xb + (size_t)tok * K + k0);
    } else {
      int rr = (gr < count) ? gr : m0;
      arow[i] = (const char*)(hbuf + (size_t)(oe + rr) * K + k0);
    }
    brow[i] = (const char*)(WT + (size_t)e * N * K + (size_t)(n0 + r) * K + k0);
  }

  auto stage = [&](int buf, int t) {
    const int kb = t * 128;   // t*BK*2 bytes
#pragma unroll
    for (int i = 0; i < 4; ++i)
      gl16(arow[i] + kb + sgoff, (char*)&sA[buf][0] + (i * 64 + wv * 8) * 128);
#pragma unroll
    for (int i = 0; i < 4; ++i)
      gl16(brow[i] + kb + sgoff, (char*)&sB[buf][0] + (i * 64 + wv * 8) * 128);
  };

  // fragment addressing
  const int lrow = lane & 15;
  const int kg   = lane >> 4;
  const int fswz = (lrow & 7) << 4;

  f32x4 acc[8][4];
#pragma unroll
  for (int i = 0; i < 8; ++i)
#pragma unroll
    for (int j = 0; j < 4; ++j) acc[i][j] = (f32x4){0.f, 0.f, 0.f, 0.f};

  stage(0, 0);
  stage(1, 1);                                   // 16 loads outstanding
  asm volatile("s_waitcnt vmcnt(8)" ::: "memory");  // tile 0 landed
  __builtin_amdgcn_s_barrier();
  MEMFENCE;

  for (int t = 0; t < NT; ++t) {
    const int buf = t & 1;
    // ---- read ALL fragments of tile t into registers ----
    bf16x8 af[8][2], bfm[4][2];
#pragma unroll
    for (int i = 0; i < 8; ++i) {
      const int ra = wm + i * 16 + lrow;
#pragma unroll
      for (int ks = 0; ks < 2; ++ks)
        af[i][ks] = *(const bf16x8*)((const char*)&sA[buf][0] + ra * 128 + ((ks * 64 + kg * 16) ^ fswz));
    }
#pragma unroll
    for (int j = 0; j < 4; ++j) {
      const int rb = wn + j * 16 + lrow;
#pragma unroll
      for (int ks = 0; ks < 2; ++ks)
        bfm[j][ks] = *(const bf16x8*)((const char*)&sB[buf][0] + rb * 128 + ((ks * 64 + kg * 16) ^ fswz));
    }
    MEMFENCE;
    __builtin_amdgcn_s_barrier();   // all waves have queued their reads of buf
    MEMFENCE;
    // ---- stage tile t+2 into the buffer just vacated ----
    if (t + 2 < NT) stage(buf, t + 2);
    // ---- MFMA cluster (compiler inserts lgkmcnt for the reg deps) ----
    __builtin_amdgcn_s_setprio(1);
#pragma unroll
    for (int ks = 0; ks < 2; ++ks)
#pragma unroll
      for (int i = 0; i < 8; ++i)
#pragma unroll
        for (int j = 0; j < 4; ++j)
          acc[i][j] = __builtin_amdgcn_mfma_f32_16x16x32_bf16(af[i][ks], bfm[j][ks], acc[i][j], 0, 0, 0);
    __builtin_amdgcn_s_setprio(0);
    // ---- counted wait: tile t+1 complete, t+2 stays in flight ----
    if (t + 2 < NT) {
      asm volatile("s_waitcnt vmcnt(8)" ::: "memory");
    } else if (t + 1 < NT) {
      asm volatile("s_waitcnt vmcnt(0)" ::: "memory");
    }
    MEMFENCE;
    __builtin_amdgcn_s_barrier();
    MEMFENCE;
  }

  // ---- epilogue ----
  const int rbase = 4 * kg;
#pragma unroll
  for (int i = 0; i < 8; ++i) {
#pragma unroll
    for (int r = 0; r < 4; ++r) {
      int row  = wm + i * 16 + rbase + r;
      int grow = m0 + row;
      if (grow < count) {
#pragma unroll
        for (int j = 0; j < 4; ++j) {
          int col  = wn + j * 16 + lrow;
          int gcol = n0 + col;
          float bv = (SPLITK == 1 || sp == 0) ? bias[(size_t)e * N + gcol] : 0.f;
          float v = acc[i][j][r] + bv;
          if (LAYER == 1) {
            v = v > 0.f ? v : 0.f;
            hout[(size_t)(oe + grow) * H_ + gcol] = f2bf(v);
          } else {
            int tok = lst[grow];
            atomicAdd(&out[(size_t)tok * D_ + gcol], v);
          }
        }
      }
    }
  }
}

extern "C" void kernel_launch(void* const* d_in, const int* in_sizes, int n_in,
                              void* d_out, int out_size, void* d_ws, size_t ws_size,
                              hipStream_t stream) {
  (void)in_sizes; (void)n_in; (void)out_size; (void)ws_size;
  const float* x  = (const float*)d_in[0];
  const float* W1 = (const float*)d_in[1];
  const float* b1 = (const float*)d_in[2];
  const float* W2 = (const float*)d_in[3];
  const float* b2 = (const float*)d_in[4];
  const float* Wg = (const float*)d_in[5];
  const float* bg = (const float*)d_in[6];

  float* out    = (float*)d_out;               // [T,D]
  float* scores = out + (size_t)T_ * D_;       // [T,E]

  char* ws = (char*)d_ws;
  int* cnt   = (int*)ws;                                  // 32 B
  int* off   = (int*)(ws + 32);                           // 32 B
  int* lists = (int*)(ws + 64);                           // 128 KB
  unsigned short* xb   = (unsigned short*)(ws + 131200);              // 8 MB
  unsigned short* hbuf = (unsigned short*)(ws + 131200 + 8388608);    // 64 MB [8192][4096]
  unsigned short* WT   = (unsigned short*)(ws + 131200 + 8388608 + 67108864); // 64 MB shared W1T/W2T

  hipMemsetAsync(out, 0, (size_t)T_ * D_ * sizeof(float), stream);
  hipMemsetAsync(cnt, 0, 64, stream);

  conv_x_kernel<<<(T_ * D_) / (256 * 8), 256, 0, stream>>>(x, xb);
  gating_kernel<<<T_ / 4, 256, 0, stream>>>(x, Wg, bg, scores, cnt, lists);
  scan_kernel<<<1, 64, 0, stream>>>(cnt, off);

  // W1 [E,1024,4096] -> W1T [E,4096,1024]
  transpose_conv<<<dim3(H_ / 64, D_ / 64, E_), 256, 0, stream>>>(W1, WT, D_, H_);
  ffn_gemm<1, 1><<<dim3(H_ / BN, T_ / BM, E_), 512, 0, stream>>>(
      xb, hbuf, WT, b1, cnt, off, lists, hbuf, nullptr);

  // W2 [E,4096,1024] -> W2T [E,1024,4096]  (reuses WT after gemm1)
  transpose_conv<<<dim3(D_ / 64, H_ / 64, E_), 256, 0, stream>>>(W2, WT, H_, D_);
  ffn_gemm<2, 2><<<dim3((D_ / BN) * 2, T_ / BM, E_), 512, 0, stream>>>(
      xb, hbuf, WT, b2, cnt, off, lists, nullptr, out);
}